// Round 4
// baseline (262.586 us; speedup 1.0000x reference)
//
#include <hip/hip_runtime.h>
#include <cstddef>
#include <cstdint>

#define L_SEQ 1024
#define NCHUNK 64
#define CLEN 16

typedef __bf16 bf16x8 __attribute__((ext_vector_type(8)));
typedef float f32x4 __attribute__((ext_vector_type(4)));

__device__ __forceinline__ float silu_f(float x) {
    return x / (1.f + __expf(-x));
}

__device__ __forceinline__ float exp2_fast(float x) {
    return exp2f(x);
}

__device__ __forceinline__ unsigned short f2bf(float x) {
    union { float f; unsigned int u; } v; v.f = x;
    unsigned int r = (v.u + 0x7fffu + ((v.u >> 16) & 1u)) >> 16;
    return (unsigned short)r;
}
__device__ __forceinline__ float bf2f(unsigned short h) {
    union { float f; unsigned int u; } v; v.u = ((unsigned int)h) << 16;
    return v.f;
}
__device__ __forceinline__ unsigned int packf(float x) {
    unsigned short h = f2bf(x);
    unsigned short l = f2bf(x - bf2f(h));
    return ((unsigned int)h << 16) | (unsigned int)l;
}
__device__ __forceinline__ float unpackf(unsigned int pk) {
    return bf2f((unsigned short)(pk >> 16)) + bf2f((unsigned short)(pk & 0xffffu));
}

// ---------------- f32 GEMM (used once: W_comb = W_x[:, :24] @ W_dt) ----------------
__global__ __launch_bounds__(256)
void gemm64(const float* __restrict__ A, int lda,
            const float* __restrict__ B, int ldb,
            float* __restrict__ Cf, int ldc,
            int M, int N, int K)
{
    __shared__ float As[16][68];
    __shared__ float Bs[16][64];
    const int tid = threadIdx.x;
    const int tx = tid & 15, ty = tid >> 4;
    const int m0 = blockIdx.y * 64, n0 = blockIdx.x * 64;
    const int arow = tid >> 2, acol = (tid & 3) << 2;
    const int brow = tid >> 4, bcol = (tid & 15) << 2;
    float acc[4][4] = {};
    const float* Ap = A + (size_t)(m0 + arow) * lda + acol;
    const float* Bp = B + (size_t)brow * ldb + n0 + bcol;
    const bool bok = (n0 + bcol) < N;
    for (int k0 = 0; k0 < K; k0 += 16) {
        float4 av = make_float4(0.f, 0.f, 0.f, 0.f);
        float4 bv = make_float4(0.f, 0.f, 0.f, 0.f);
        if (k0 + acol < K) av = *(const float4*)(Ap + k0);
        if (bok && (k0 + brow) < K) bv = *(const float4*)(Bp + (size_t)k0 * ldb);
        As[acol + 0][arow] = av.x;
        As[acol + 1][arow] = av.y;
        As[acol + 2][arow] = av.z;
        As[acol + 3][arow] = av.w;
        *(float4*)&Bs[brow][bcol] = bv;
        __syncthreads();
        #pragma unroll
        for (int k = 0; k < 16; ++k) {
            float4 a4 = *(const float4*)&As[k][ty * 4];
            float4 b4 = *(const float4*)&Bs[k][tx * 4];
            float aa[4] = {a4.x, a4.y, a4.z, a4.w};
            float bb[4] = {b4.x, b4.y, b4.z, b4.w};
            #pragma unroll
            for (int i = 0; i < 4; ++i)
                #pragma unroll
                for (int j = 0; j < 4; ++j)
                    acc[i][j] = fmaf(aa[i], bb[j], acc[i][j]);
        }
        __syncthreads();
    }
    const int nn = n0 + tx * 4;
    if (nn >= N) return;
    #pragma unroll
    for (int i = 0; i < 4; ++i) {
        int m = m0 + ty * 4 + i;
        *(float4*)(Cf + (size_t)m * ldc + nn) =
            make_float4(acc[i][0], acc[i][1], acc[i][2], acc[i][3]);
    }
}

// ---------------- bf16x3 MFMA GEMM: 128x128 tile, BK=32, 4 waves ----------------
// EPI 0: f32 out (+opt bias). EPI 1: bf16 hi/lo planes (+bias).
// EPI 2: cols<32 -> Cf2 (stride 32, f32); cols 32..799 -> softplus(o + bias[nn-32]) -> Cf (ldc).
template<bool APK, int EPI>
__global__ __launch_bounds__(256)
void gemm_bf3(const unsigned short* __restrict__ Ahi,
              const unsigned short* __restrict__ Alo,
              const unsigned int* __restrict__ Apk, int lda,
              const unsigned short* __restrict__ Bthi,
              const unsigned short* __restrict__ Btlo,
              const float* __restrict__ bias,
              float* __restrict__ Cf, float* __restrict__ Cf2,
              unsigned short* __restrict__ Chi, unsigned short* __restrict__ Clo,
              int ldc, int K)
{
    __shared__ unsigned short As[2][128][40];
    __shared__ unsigned short Bs[2][128][40];
    const int tid = threadIdx.x;
    const int lane = tid & 63;
    const int wave = tid >> 6;
    const int wm = wave >> 1, wn = wave & 1;
    const int m0 = blockIdx.y * 128, n0 = blockIdx.x * 128;
    const int srow = tid >> 1, sko = (tid & 1) * 16;

    f32x4 acc[4][4];
    #pragma unroll
    for (int i = 0; i < 4; ++i)
        #pragma unroll
        for (int j = 0; j < 4; ++j) {
            f32x4 z = {0.f, 0.f, 0.f, 0.f};
            acc[i][j] = z;
        }

    const size_t aoff = (size_t)(m0 + srow) * lda + sko;
    const size_t boff = (size_t)(n0 + srow) * K + sko;

    for (int k0 = 0; k0 < K; k0 += 32) {
        if constexpr (!APK) {
            uint4 h0 = *(const uint4*)(Ahi + aoff + k0);
            uint4 h1 = *(const uint4*)(Ahi + aoff + k0 + 8);
            uint4 l0 = *(const uint4*)(Alo + aoff + k0);
            uint4 l1 = *(const uint4*)(Alo + aoff + k0 + 8);
            *(uint4*)&As[0][srow][sko]     = h0;
            *(uint4*)&As[0][srow][sko + 8] = h1;
            *(uint4*)&As[1][srow][sko]     = l0;
            *(uint4*)&As[1][srow][sko + 8] = l1;
        } else {
            const unsigned int* ap = Apk + aoff + k0;
            uint4 p0 = *(const uint4*)(ap);
            uint4 p1 = *(const uint4*)(ap + 4);
            uint4 p2 = *(const uint4*)(ap + 8);
            uint4 p3 = *(const uint4*)(ap + 12);
            uint4 h0, h1, l0, l1;
            h0.x = (p0.x >> 16) | (p0.y & 0xffff0000u);
            h0.y = (p0.z >> 16) | (p0.w & 0xffff0000u);
            h0.z = (p1.x >> 16) | (p1.y & 0xffff0000u);
            h0.w = (p1.z >> 16) | (p1.w & 0xffff0000u);
            h1.x = (p2.x >> 16) | (p2.y & 0xffff0000u);
            h1.y = (p2.z >> 16) | (p2.w & 0xffff0000u);
            h1.z = (p3.x >> 16) | (p3.y & 0xffff0000u);
            h1.w = (p3.z >> 16) | (p3.w & 0xffff0000u);
            l0.x = (p0.x & 0xffffu) | (p0.y << 16);
            l0.y = (p0.z & 0xffffu) | (p0.w << 16);
            l0.z = (p1.x & 0xffffu) | (p1.y << 16);
            l0.w = (p1.z & 0xffffu) | (p1.w << 16);
            l1.x = (p2.x & 0xffffu) | (p2.y << 16);
            l1.y = (p2.z & 0xffffu) | (p2.w << 16);
            l1.z = (p3.x & 0xffffu) | (p3.y << 16);
            l1.w = (p3.z & 0xffffu) | (p3.w << 16);
            *(uint4*)&As[0][srow][sko]     = h0;
            *(uint4*)&As[0][srow][sko + 8] = h1;
            *(uint4*)&As[1][srow][sko]     = l0;
            *(uint4*)&As[1][srow][sko + 8] = l1;
        }
        {
            uint4 bh0 = *(const uint4*)(Bthi + boff + k0);
            uint4 bh1 = *(const uint4*)(Bthi + boff + k0 + 8);
            uint4 bl0 = *(const uint4*)(Btlo + boff + k0);
            uint4 bl1 = *(const uint4*)(Btlo + boff + k0 + 8);
            *(uint4*)&Bs[0][srow][sko]     = bh0;
            *(uint4*)&Bs[0][srow][sko + 8] = bh1;
            *(uint4*)&Bs[1][srow][sko]     = bl0;
            *(uint4*)&Bs[1][srow][sko + 8] = bl1;
        }
        __syncthreads();
        const int fr = lane & 15, kq = lane >> 4;
        bf16x8 aH[4], aL[4];
        #pragma unroll
        for (int i = 0; i < 4; ++i) {
            aH[i] = *(const bf16x8*)&As[0][wm * 64 + i * 16 + fr][kq * 8];
            aL[i] = *(const bf16x8*)&As[1][wm * 64 + i * 16 + fr][kq * 8];
        }
        #pragma unroll
        for (int j = 0; j < 4; ++j) {
            bf16x8 bH = *(const bf16x8*)&Bs[0][wn * 64 + j * 16 + fr][kq * 8];
            bf16x8 bL = *(const bf16x8*)&Bs[1][wn * 64 + j * 16 + fr][kq * 8];
            #pragma unroll
            for (int i = 0; i < 4; ++i)
                acc[i][j] = __builtin_amdgcn_mfma_f32_16x16x32_bf16(aH[i], bH, acc[i][j], 0, 0, 0);
            #pragma unroll
            for (int i = 0; i < 4; ++i)
                acc[i][j] = __builtin_amdgcn_mfma_f32_16x16x32_bf16(aL[i], bH, acc[i][j], 0, 0, 0);
            #pragma unroll
            for (int i = 0; i < 4; ++i)
                acc[i][j] = __builtin_amdgcn_mfma_f32_16x16x32_bf16(aH[i], bL, acc[i][j], 0, 0, 0);
        }
        __syncthreads();
    }
    const int col = lane & 15, rq = lane >> 4;
    #pragma unroll
    for (int j = 0; j < 4; ++j) {
        int nn = n0 + wn * 64 + j * 16 + col;
        float bv = 0.f;
        if constexpr (EPI == 0 || EPI == 1) { if (bias) bv = bias[nn]; }
        if constexpr (EPI == 2) { if (nn >= 32 && nn < 800) bv = bias[nn - 32]; }
        #pragma unroll
        for (int i = 0; i < 4; ++i) {
            int mb = m0 + wm * 64 + i * 16 + rq * 4;
            #pragma unroll
            for (int r = 0; r < 4; ++r) {
                float o = acc[i][j][r] + bv;
                if constexpr (EPI == 0) {
                    Cf[(size_t)(mb + r) * ldc + nn] = o;
                } else if constexpr (EPI == 1) {
                    unsigned short h = f2bf(o);
                    Chi[(size_t)(mb + r) * ldc + nn] = h;
                    Clo[(size_t)(mb + r) * ldc + nn] = f2bf(o - bf2f(h));
                } else {
                    if (nn < 32) {
                        Cf2[(size_t)(mb + r) * 32 + nn] = o;
                    } else if (nn < 800) {
                        float sp = fmaxf(o, 0.f) + log1pf(expf(-fabsf(o)));
                        Cf[(size_t)(mb + r) * ldc + (nn - 32)] = sp;
                    }
                }
            }
        }
    }
}

// ---------------- transpose + hi/lo split of weights: W[K][N] -> Wt[N][K] ----------------
__global__ __launch_bounds__(256)
void wcvt(const float* __restrict__ W, unsigned short* __restrict__ Thi,
          unsigned short* __restrict__ Tlo, int K, int N)
{
    __shared__ float t[32][33];
    const int tid = threadIdx.x;
    const int n0 = blockIdx.x * 32, k0 = blockIdx.y * 32;
    const int r = tid >> 3, c4 = (tid & 7) * 4;
    float4 v = *(const float4*)(W + (size_t)(k0 + r) * N + n0 + c4);
    t[r][c4 + 0] = v.x; t[r][c4 + 1] = v.y; t[r][c4 + 2] = v.z; t[r][c4 + 3] = v.w;
    __syncthreads();
    unsigned short hs[4], ls[4];
    #pragma unroll
    for (int j = 0; j < 4; ++j) {
        float x = t[c4 + j][r];
        hs[j] = f2bf(x);
        ls[j] = f2bf(x - bf2f(hs[j]));
    }
    size_t o = (size_t)(n0 + r) * K + k0 + c4;
    uint2 hv, lv;
    hv.x = (unsigned)hs[0] | ((unsigned)hs[1] << 16);
    hv.y = (unsigned)hs[2] | ((unsigned)hs[3] << 16);
    lv.x = (unsigned)ls[0] | ((unsigned)ls[1] << 16);
    lv.y = (unsigned)ls[2] | ((unsigned)ls[3] << 16);
    *(uint2*)(Thi + o) = hv;
    *(uint2*)(Tlo + o) = lv;
}

// rows 0..31 of Btc: W_x B/C slice transposed; rows 800..895: zero pad
__global__ __launch_bounds__(256)
void pad_btc(const float* __restrict__ W_x,
             unsigned short* __restrict__ Thi, unsigned short* __restrict__ Tlo)
{
    const int flat = blockIdx.x * 256 + threadIdx.x;   // 128*768
    const int r = flat / 768, k = flat % 768;
    const int row = (r < 32) ? r : (768 + r);          // 0..31 or 800..895
    float val = (r < 32) ? W_x[(size_t)k * 56 + 24 + r] : 0.f;
    unsigned short h = f2bf(val);
    Thi[(size_t)row * 768 + k] = h;
    Tlo[(size_t)row * 768 + k] = f2bf(val - bf2f(h));
}

// pack [ev|rgb] concat as (hi<<16|lo) uints: apk[4096][256]
__global__ __launch_bounds__(256)
void embed_pack(const float* __restrict__ ev, const float* __restrict__ rgb,
                unsigned int* __restrict__ apk)
{
    const int m = blockIdx.x, kk = threadIdx.x;
    float val = (kk < 128) ? ev[(size_t)m * 128 + kk] : rgb[(size_t)m * 128 + kk - 128];
    apk[(size_t)m * 256 + kk] = packf(val);
}

// block-diag embed weight: Wcat_t[384][256] hi/lo + concat bias[384]
__global__ __launch_bounds__(256)
void wcat_cvt(const float* __restrict__ W_ev, const float* __restrict__ W_rgb,
              const float* __restrict__ b_ev, const float* __restrict__ b_rgb,
              unsigned short* __restrict__ Thi, unsigned short* __restrict__ Tlo,
              float* __restrict__ biascat)
{
    const int flat = blockIdx.x * 256 + threadIdx.x;
    if (flat < 384 * 256) {
        const int n = flat >> 8, k = flat & 255;
        float val = 0.f;
        if (n < 192) { if (k < 128) val = W_ev[(size_t)k * 192 + n]; }
        else         { if (k >= 128) val = W_rgb[(size_t)(k - 128) * 192 + (n - 192)]; }
        unsigned short h = f2bf(val);
        Thi[flat] = h;
        Tlo[flat] = f2bf(val - bf2f(h));
    } else if (flat < 384 * 256 + 384) {
        const int i = flat - 384 * 256;
        biascat[i] = (i < 192) ? b_ev[i] : b_rgb[i - 192];
    }
}

// ---------------- LayerNorm over 384, on hi/lo planes, in place ----------------
__global__ __launch_bounds__(256)
void ln2(unsigned short* __restrict__ hi, unsigned short* __restrict__ lo,
         const float* __restrict__ g, const float* __restrict__ b)
{
    const int lane = threadIdx.x & 63;
    const int row = blockIdx.x * 4 + (threadIdx.x >> 6);
    unsigned short* ph = hi + (size_t)row * 384;
    unsigned short* pl = lo + (size_t)row * 384;
    float v[6];
    #pragma unroll
    for (int i = 0; i < 6; ++i) {
        int c = i * 64 + lane;
        v[i] = bf2f(ph[c]) + bf2f(pl[c]);
    }
    float s = v[0] + v[1] + v[2] + v[3] + v[4] + v[5];
    #pragma unroll
    for (int m = 32; m >= 1; m >>= 1) s += __shfl_xor(s, m);
    const float mu = s * (1.f / 384.f);
    float q = 0.f;
    #pragma unroll
    for (int i = 0; i < 6; ++i) { float dv = v[i] - mu; q = fmaf(dv, dv, q); }
    #pragma unroll
    for (int m = 32; m >= 1; m >>= 1) q += __shfl_xor(q, m);
    const float inv = 1.f / sqrtf(q * (1.f / 384.f) + 1e-5f);
    #pragma unroll
    for (int i = 0; i < 6; ++i) {
        int c = i * 64 + lane;
        float o = (v[i] - mu) * inv * g[c] + b[c];
        unsigned short h = f2bf(o);
        ph[c] = h;
        pl[c] = f2bf(o - bf2f(h));
    }
}

// ------- depthwise causal conv(4) + SiLU -> packed u (streaming, 16 tokens/thread) -------
__global__ __launch_bounds__(256)
void conv_pack(const float* __restrict__ xr, const float* __restrict__ conv_w,
               const float* __restrict__ conv_b, unsigned int* __restrict__ upk)
{
    const int d = blockIdx.x * 256 + threadIdx.x;
    const int t0 = blockIdx.z * L_SEQ + blockIdx.y * 16;
    const float w0 = conv_w[d * 4 + 0], w1 = conv_w[d * 4 + 1];
    const float w2 = conv_w[d * 4 + 2], w3 = conv_w[d * 4 + 3];
    const float cb = conv_b[d];
    const float* xp = xr + (size_t)t0 * 1536 + d;
    float x1, x2, x3;
    if (blockIdx.y == 0) { x1 = x2 = x3 = 0.f; }
    else {
        x1 = xp[-1 * 1536];
        x2 = xp[-2 * 1536];
        x3 = xp[-3 * 1536];
    }
    unsigned int* op = upk + (size_t)t0 * 768 + d;
    #pragma unroll 4
    for (int i = 0; i < 16; ++i) {
        float cur = xp[i * 1536];
        float a = cb;
        a = fmaf(x3, w0, a);
        a = fmaf(x2, w1, a);
        a = fmaf(x1, w2, a);
        a = fmaf(cur, w3, a);
        op[i * 768] = packf(silu_f(a));
        x3 = x2; x2 = x1; x1 = cur;
    }
}

// ---------------- chunked selective scan ----------------
__global__ __launch_bounds__(256)
void scan_a2(const float* __restrict__ delta, const unsigned int* __restrict__ upk,
             const float* __restrict__ bc, const float* __restrict__ A_log,
             float* __restrict__ dsum_out, float* __restrict__ Bc)
{
    __shared__ float Bsh[CLEN][16];
    const int tid = threadIdx.x;
    const int d = blockIdx.x * 256 + tid;
    const int c = blockIdx.y, b = blockIdx.z;
    const int row0 = b * L_SEQ + c * CLEN;
    {
        int t = tid >> 4, n = tid & 15;
        Bsh[t][n] = bc[(size_t)(row0 + t) * 32 + n];
    }
    float AL2[16];
    {
        const float* ap = A_log + d * 16;
        #pragma unroll
        for (int n = 0; n < 16; ++n)
            AL2[n] = -__expf(ap[n]) * 1.44269504f;
    }
    __syncthreads();
    float h[16];
    #pragma unroll
    for (int n = 0; n < 16; ++n) h[n] = 0.f;
    float dsum = 0.f;
    const float* dp = delta + (size_t)row0 * 768 + d;
    const unsigned int* up = upk + (size_t)row0 * 768 + d;
    #pragma unroll 4
    for (int t = 0; t < CLEN; ++t) {
        float dt = dp[t * 768];
        float ut = unpackf(up[t * 768]);
        float du = dt * ut;
        dsum += dt;
        #pragma unroll
        for (int n = 0; n < 16; ++n) {
            float dA = exp2_fast(dt * AL2[n]);
            h[n] = fmaf(dA, h[n], du * Bsh[t][n]);
        }
    }
    dsum_out[(size_t)(b * 768 + d) * NCHUNK + c] = dsum;
    float* bcp = Bc + (((size_t)(b * 768 + d)) * NCHUNK + c) * 16;
    #pragma unroll
    for (int n = 0; n < 16; ++n) bcp[n] = h[n];
}

__global__ __launch_bounds__(256)
void scan_b2(const float* __restrict__ dsum, const float* __restrict__ A_log,
             float* __restrict__ BcHin)
{
    const size_t flat = (size_t)blockIdx.x * 256 + threadIdx.x;  // 0..49151
    const size_t bd = flat >> 4;
    const int n = (int)(flat & 15);
    const int d = (int)(bd % 768);
    const float AL2 = -__expf(A_log[d * 16 + n]) * 1.44269504f;
    const float* dsp = dsum + bd * NCHUNK;
    const size_t base = bd * (NCHUNK * 16) + n;
    float h = 0.f;
    for (int c = 0; c < NCHUNK; ++c) {
        size_t i = base + (size_t)c * 16;
        float a = exp2_fast(AL2 * dsp[c]);
        float bb = BcHin[i];
        BcHin[i] = h;
        h = fmaf(a, h, bb);
    }
}

__global__ __launch_bounds__(256)
void scan_c2(float* __restrict__ delta, const unsigned int* __restrict__ upk,
             const float* __restrict__ bc, const float* __restrict__ A_log,
             const float* __restrict__ Hin, const float* __restrict__ D_skip,
             const float* __restrict__ xr)   // res in cols 768..1535; y packed over delta
{
    __shared__ float Bsh[CLEN][16];
    __shared__ float Csh[CLEN][16];
    const int tid = threadIdx.x;
    const int d = blockIdx.x * 256 + tid;
    const int c = blockIdx.y, b = blockIdx.z;
    const int row0 = b * L_SEQ + c * CLEN;
    {
        int t = tid >> 4, n = tid & 15;
        const float* xp = bc + (size_t)(row0 + t) * 32;
        Bsh[t][n] = xp[n];
        Csh[t][n] = xp[16 + n];
    }
    float AL2[16];
    {
        const float* ap = A_log + d * 16;
        #pragma unroll
        for (int n = 0; n < 16; ++n)
            AL2[n] = -__expf(ap[n]) * 1.44269504f;
    }
    float h[16];
    {
        const float* hp = Hin + (((size_t)(b * 768 + d)) * NCHUNK + c) * 16;
        #pragma unroll
        for (int n = 0; n < 16; ++n) h[n] = hp[n];
    }
    const float Ds = D_skip[d];
    __syncthreads();
    float* dp = delta + (size_t)row0 * 768 + d;
    const unsigned int* up = upk + (size_t)row0 * 768 + d;
    const float* rp = xr + (size_t)row0 * 1536 + 768 + d;
    #pragma unroll 4
    for (int t = 0; t < CLEN; ++t) {
        float dt = dp[t * 768];
        float ut = unpackf(up[t * 768]);
        float du = dt * ut;
        float y = 0.f;
        #pragma unroll
        for (int n = 0; n < 16; ++n) {
            float dA = exp2_fast(dt * AL2[n]);
            h[n] = fmaf(dA, h[n], du * Bsh[t][n]);
            y = fmaf(h[n], Csh[t][n], y);
        }
        float res = rp[t * 1536];
        float gy = fmaf(ut, Ds, y) * silu_f(res);
        dp[t * 768] = __builtin_bit_cast(float, packf(gy));   // y packed in place
    }
}

extern "C" void kernel_launch(void* const* d_in, const int* in_sizes, int n_in,
                              void* d_out, int out_size, void* d_ws, size_t ws_size,
                              hipStream_t stream)
{
    const float* ev     = (const float*)d_in[0];
    const float* rgb    = (const float*)d_in[1];
    const float* W_ev   = (const float*)d_in[2];
    const float* b_ev   = (const float*)d_in[3];
    const float* W_rgb  = (const float*)d_in[4];
    const float* b_rgb  = (const float*)d_in[5];
    const float* ln_g   = (const float*)d_in[6];
    const float* ln_b   = (const float*)d_in[7];
    const float* W_proj = (const float*)d_in[8];
    const float* b_proj = (const float*)d_in[9];
    const float* W_in   = (const float*)d_in[10];
    const float* conv_w = (const float*)d_in[11];
    const float* conv_b = (const float*)d_in[12];
    const float* W_x    = (const float*)d_in[13];
    const float* W_dt   = (const float*)d_in[14];
    const float* b_dt   = (const float*)d_in[15];
    const float* A_log  = (const float*)d_in[16];
    const float* D_skip = (const float*)d_in[17];
    const float* W_out  = (const float*)d_in[18];
    float* out = (float*)d_out;

    // workspace layout (float units); high-water 17,825,792 floats = 71.3 MB (same as r3)
    float* ws = (float*)d_ws;
    // zone 0 [0 .. 1,572,864): xf hi/lo planes (die after proj); later dsum + bc
    unsigned short* xfh  = (unsigned short*)ws;
    unsigned short* xfl  = xfh + 1572864;
    float* dsum          = ws;                         // 196,608 fl (scan_a2..b2)
    float* bc            = ws + 196608;                // 131,072 fl (big-gemm..scan_c2)
    // zone 1 [1,572,864 .. 4,718,592): xmm planes (die after W_in); then upk
    unsigned short* xmmh = (unsigned short*)(ws + 1572864);
    unsigned short* xmml = xmmh + 1572864;
    unsigned int* upk    = (unsigned int*)(ws + 1572864);   // 3,145,728 uints
    // zone 2 [4,718,592 .. 11,010,048): xr f32 [4096][1536]; apk aliases head pre-W_in
    float* xr            = ws + 4718592;
    unsigned int* apk    = (unsigned int*)xr;          // 1,048,576 uints (dies after embed)
    // zone 3 [11,239,424 .. 14,385,152): delta f32 [4096][768] (y packed in place later)
    float* delta         = ws + 11239424;
    // zone 4 [14,385,152 .. 17,530,880): BcHin (written at scan_a2); early aliases:
    float* BcHin         = ws + 14385152;
    unsigned short* wtp_hi = (unsigned short*)BcHin;                 // 147,456 sh
    unsigned short* wtp_lo = wtp_hi + 147456;
    unsigned short* wti_hi = wtp_lo + 147456;                        // 589,824 sh
    unsigned short* wti_lo = wti_hi + 589824;
    float* Wcf             = BcHin + 737280;                         // 589,824 fl
    unsigned short* btc_hi = (unsigned short*)(BcHin + 1327104);     // 896*768 sh
    unsigned short* btc_lo = btc_hi + 688128;
    unsigned short* wct_hi = (unsigned short*)(BcHin + 2015232);     // 384*256 sh
    unsigned short* wct_lo = wct_hi + 98304;
    float* biascat         = BcHin + 2113536;                        // 384 fl
    // zone 5 [17,530,880 .. 17,825,792): wto hi/lo (live till out-gemm)
    unsigned short* wto_hi = (unsigned short*)(ws + 17530880);
    unsigned short* wto_lo = wto_hi + 294912;

    dim3 blk(256);

    // --- weight prep ---
    wcvt<<<dim3(12, 12), blk, 0, stream>>>(W_proj, wtp_hi, wtp_lo, 384, 384);
    wcvt<<<dim3(48, 12), blk, 0, stream>>>(W_in,   wti_hi, wti_lo, 384, 1536);
    wcvt<<<dim3(12, 24), blk, 0, stream>>>(W_out,  wto_hi, wto_lo, 768, 384);
    // W_comb = W_x[:, :24] @ W_dt  [768 x 768] f32
    gemm64<<<dim3(12, 12), blk, 0, stream>>>(W_x, 56, W_dt, 768, Wcf, 768, 768, 768, 24);
    // Btc[896][768]: rows 0..31 = W_x B/C slice; 32..799 = W_comb^T; 800..895 = 0
    pad_btc<<<384, blk, 0, stream>>>(W_x, btc_hi, btc_lo);
    wcvt<<<dim3(24, 24), blk, 0, stream>>>(Wcf, btc_hi + 32 * 768, btc_lo + 32 * 768, 768, 768);
    // embed operands
    embed_pack<<<4096, blk, 0, stream>>>(ev, rgb, apk);
    wcat_cvt<<<386, blk, 0, stream>>>(W_ev, W_rgb, b_ev, b_rgb, wct_hi, wct_lo, biascat);

    // --- pipeline ---
    // embeds: [ev|rgb] @ blockdiag -> xf planes
    gemm_bf3<true, 1><<<dim3(3, 32), blk, 0, stream>>>(
        nullptr, nullptr, apk, 256, wct_hi, wct_lo, biascat,
        nullptr, nullptr, xfh, xfl, 384, 256);
    ln2<<<1024, blk, 0, stream>>>(xfh, xfl, ln_g, ln_b);
    // proj -> xmm planes
    gemm_bf3<false, 1><<<dim3(3, 32), blk, 0, stream>>>(
        xfh, xfl, nullptr, 384, wtp_hi, wtp_lo, b_proj,
        nullptr, nullptr, xmmh, xmml, 384, 384);
    // W_in -> xr f32
    gemm_bf3<false, 0><<<dim3(12, 32), blk, 0, stream>>>(
        xmmh, xmml, nullptr, 384, wti_hi, wti_lo, nullptr,
        xr, nullptr, nullptr, nullptr, 1536, 384);
    // conv + silu -> packed u (overwrites dead xmm zone)
    conv_pack<<<dim3(3, 64, 4), blk, 0, stream>>>(xr, conv_w, conv_b, upk);
    // fused x_dbl B/C + delta: u @ [Wx_BC | W_comb] -> bc (cols<32), softplus->delta
    gemm_bf3<true, 2><<<dim3(7, 32), blk, 0, stream>>>(
        nullptr, nullptr, upk, 768, btc_hi, btc_lo, b_dt,
        delta, bc, nullptr, nullptr, 768, 768);
    // chunked scan
    scan_a2<<<dim3(3, NCHUNK, 4), blk, 0, stream>>>(delta, upk, bc, A_log, dsum, BcHin);
    scan_b2<<<192, blk, 0, stream>>>(dsum, A_log, BcHin);
    scan_c2<<<dim3(3, NCHUNK, 4), blk, 0, stream>>>(delta, upk, bc, A_log, BcHin, D_skip, xr);
    // out GEMM (packed y from delta zone) -> d_out
    gemm_bf3<true, 0><<<dim3(3, 32), blk, 0, stream>>>(
        nullptr, nullptr, (const unsigned int*)delta, 768, wto_hi, wto_lo, nullptr,
        out, nullptr, nullptr, nullptr, 384, 768);
}